// Round 1
// baseline (102.212 us; speedup 1.0000x reference)
//
#include <hip/hip_runtime.h>
#include <math.h>

#define GN 8192
#define GF 64
#define GFIN 256
#define NEG 0.2f
#define NCH 128
#define CHSZ 64   // GN / NCH

// workspace layout in floats
#define OFF_WH   0
#define OFF_S1   (GN*GF)                    // 524288
#define OFF_S2   (OFF_S1 + GN)
#define OFF_ZS   (OFF_S2 + GN)
#define OFF_IDX  (OFF_ZS + GN)              // int32
#define OFF_VA   (OFF_IDX + GN)
#define OFF_VB   (OFF_VA + (GN+1)*GF)
#define OFF_SA   (OFF_VB + (GN+1)*GF)
#define OFF_PB   (OFF_SA + (GN+1))
#define OFF_CHA  (OFF_PB + (GN+1))
#define OFF_CHB  (OFF_CHA + NCH*65)
#define OFF_OA   (OFF_CHB + NCH*65)
#define OFF_OB   (OFF_OA + NCH*65)

// Kernel 1: Wh = h @ W  [N,64], s1 = Wh@a1, s2 = Wh@a2
__global__ __launch_bounds__(512) void k_wh(const float* __restrict__ h,
        const float* __restrict__ W, const float* __restrict__ a,
        float* __restrict__ Wh, float* __restrict__ s1, float* __restrict__ s2) {
    __shared__ float hs[32][GFIN];           // 32 KB
    int t = threadIdx.x;
    int row0 = blockIdx.x * 32;
    const float4* h4 = (const float4*)(h + (size_t)row0 * GFIN);
    float4* hs4 = (float4*)&hs[0][0];
    for (int i = t; i < 32*GFIN/4; i += 512) hs4[i] = h4[i];
    __syncthreads();
    int wave = t >> 6, lane = t & 63;
    float acc[4] = {0.f, 0.f, 0.f, 0.f};
    #pragma unroll 8
    for (int k = 0; k < GFIN; ++k) {
        float wv = W[k*GF + lane];
        #pragma unroll
        for (int q = 0; q < 4; ++q) acc[q] += hs[wave*4+q][k] * wv;
    }
    float a1 = a[lane], a2 = a[GF + lane];
    #pragma unroll
    for (int q = 0; q < 4; ++q) {
        int row = row0 + wave*4 + q;
        Wh[(size_t)row*GF + lane] = acc[q];
        float v1 = acc[q]*a1, v2 = acc[q]*a2;
        #pragma unroll
        for (int o = 32; o > 0; o >>= 1) { v1 += __shfl_xor(v1, o); v2 += __shfl_xor(v2, o); }
        if (lane == 0) { s1[row] = v1; s2[row] = v2; }
    }
}

// Kernel 2: rank-sort s2 (strict total order with index tiebreak -> permutation)
__global__ __launch_bounds__(256) void k_rank(const float* __restrict__ s2v,
        float* __restrict__ zs, int* __restrict__ idx) {
    __shared__ float z[GN];
    int t = threadIdx.x;
    for (int m = t; m < GN; m += 256) z[m] = s2v[m];
    __syncthreads();
    int jl = t >> 3, s = t & 7;              // 32 j's per block, 8 slices each
    int j = blockIdx.x * 32 + jl;
    float zj = z[j];
    int cnt = 0;
    // m = i*8 + s: 8 distinct banks per wave (bank-conflict-free broadcast groups)
    for (int i = 0; i < GN/8; ++i) {
        int m = i*8 + s;
        float zm = z[m];
        cnt += (zm < zj) || (zm == zj && m < j);
    }
    cnt += __shfl_xor(cnt, 1);
    cnt += __shfl_xor(cnt, 2);
    cnt += __shfl_xor(cnt, 4);
    if (s == 0) { zs[cnt] = zj; idx[cnt] = j; }
}

// Kernel 3: per-chunk totals of termA*w and termB*w (c=64 is the scalar channel)
__global__ __launch_bounds__(128) void k_chunk(const float* __restrict__ Wh,
        const float* __restrict__ zs, const int* __restrict__ idx,
        float* __restrict__ chA, float* __restrict__ chB) {
    int c = threadIdx.x;
    if (c >= 65) return;
    int ch = blockIdx.x;
    float Z = zs[GN-1];
    float aAcc = 0.f, bAcc = 0.f;
    for (int q = 0; q < CHSZ; ++q) {
        int r = ch*CHSZ + q;
        float zr = zs[r];
        int ir = idx[r];
        float tA = expf(zr - Z);
        float tB = expf(NEG * (zr - Z));
        float w = (c < 64) ? Wh[(size_t)ir*GF + c] : 1.0f;
        aAcc += tA * w;
        bAcc += tB * w;
    }
    chA[ch*65 + c] = aAcc;
    chB[ch*65 + c] = bAcc;
}

// Kernel 4: scan chunk totals (exclusive prefix for B fwd, exclusive suffix for A bwd)
__global__ __launch_bounds__(128) void k_scan(const float* __restrict__ chA,
        const float* __restrict__ chB, float* __restrict__ offA, float* __restrict__ offB,
        float* __restrict__ VA, float* __restrict__ VB,
        float* __restrict__ SA, float* __restrict__ PB) {
    int c = threadIdx.x;
    if (c >= 65) return;
    float run = 0.f;
    for (int ch = 0; ch < NCH; ++ch) { offB[ch*65 + c] = run; run += chB[ch*65 + c]; }
    if (c < 64) VB[(size_t)GN*GF + c] = run; else PB[GN] = run;   // k = N boundary
    run = 0.f;
    for (int ch = NCH-1; ch >= 0; --ch) { offA[ch*65 + c] = run; run += chA[ch*65 + c]; }
    if (c < 64) VA[(size_t)GN*GF + c] = 0.f; else SA[GN] = 0.f;
}

// Kernel 5: fill full prefix/suffix arrays
// VA[k] = sum_{r>=k} expf(z_r - Z) * w_r   (inclusive suffix)
// VB[k] = sum_{r<k}  expf(0.2(z_r - Z)) * w_r (exclusive prefix)
__global__ __launch_bounds__(128) void k_fill(const float* __restrict__ Wh,
        const float* __restrict__ zs, const int* __restrict__ idx,
        const float* __restrict__ offA, const float* __restrict__ offB,
        float* __restrict__ VA, float* __restrict__ VB,
        float* __restrict__ SA, float* __restrict__ PB) {
    int c = threadIdx.x;
    if (c >= 65) return;
    int ch = blockIdx.x;
    float Z = zs[GN-1];
    float accA = offA[ch*65 + c];
    for (int q = CHSZ-1; q >= 0; --q) {
        int r = ch*CHSZ + q;
        float zr = zs[r]; int ir = idx[r];
        float w = (c < 64) ? Wh[(size_t)ir*GF + c] : 1.0f;
        accA += expf(zr - Z) * w;
        if (c < 64) VA[(size_t)r*GF + c] = accA; else SA[r] = accA;
    }
    float accB = offB[ch*65 + c];
    for (int q = 0; q < CHSZ; ++q) {
        int r = ch*CHSZ + q;
        float zr = zs[r]; int ir = idx[r];
        float w = (c < 64) ? Wh[(size_t)ir*GF + c] : 1.0f;
        if (c < 64) VB[(size_t)r*GF + c] = accB; else PB[r] = accB;
        accB += expf(NEG * (zr - Z)) * w;
    }
}

// Kernel 6: per-row output. one wave per row.
__global__ __launch_bounds__(256) void k_out(const float* __restrict__ s1,
        const float* __restrict__ zs,
        const float* __restrict__ VA, const float* __restrict__ VB,
        const float* __restrict__ SA, const float* __restrict__ PB,
        float* __restrict__ out) {
    int t = threadIdx.x;
    int wave = t >> 6, lane = t & 63;
    int i = blockIdx.x*4 + wave;
    float s1i = s1[i];
    float Z = zs[GN-1];
    float g = s1i + Z;
    float m = (g >= 0.f) ? g : NEG*g;        // LeakyReLU(g) = row max of e
    float aA = expf(g - m);                  // <= 1
    float aB = expf(NEG*g - m);              // <= 1
    float tgt = -s1i;
    int lo = 0, hi = GN;                     // lower_bound: first zs[k] >= -s1[i]
    while (lo < hi) { int mid = (lo+hi) >> 1; if (zs[mid] < tgt) lo = mid+1; else hi = mid; }
    int k = lo;
    float va = VA[(size_t)k*GF + lane];
    float vb = VB[(size_t)k*GF + lane];
    float sa = SA[k], pb = PB[k];
    out[(size_t)i*GF + lane] = (aA*va + aB*vb) / (aA*sa + aB*pb);
}

extern "C" void kernel_launch(void* const* d_in, const int* in_sizes, int n_in,
                              void* d_out, int out_size, void* d_ws, size_t ws_size,
                              hipStream_t stream) {
    const float* h = (const float*)d_in[0];
    // d_in[1] = adj (unused by the reference forward)
    const float* W = (const float*)d_in[2];
    const float* a = (const float*)d_in[3];
    float* ws = (float*)d_ws;
    float* Wh  = ws + OFF_WH;
    float* s1  = ws + OFF_S1;
    float* s2  = ws + OFF_S2;
    float* zs  = ws + OFF_ZS;
    int*   idx = (int*)(ws + OFF_IDX);
    float* VA  = ws + OFF_VA;
    float* VB  = ws + OFF_VB;
    float* SA  = ws + OFF_SA;
    float* PB  = ws + OFF_PB;
    float* chA = ws + OFF_CHA;
    float* chB = ws + OFF_CHB;
    float* oA  = ws + OFF_OA;
    float* oB  = ws + OFF_OB;
    float* out = (float*)d_out;

    hipLaunchKernelGGL(k_wh,    dim3(GN/32), dim3(512), 0, stream, h, W, a, Wh, s1, s2);
    hipLaunchKernelGGL(k_rank,  dim3(GN/32), dim3(256), 0, stream, s2, zs, idx);
    hipLaunchKernelGGL(k_chunk, dim3(NCH),   dim3(128), 0, stream, Wh, zs, idx, chA, chB);
    hipLaunchKernelGGL(k_scan,  dim3(1),     dim3(128), 0, stream, chA, chB, oA, oB, VA, VB, SA, PB);
    hipLaunchKernelGGL(k_fill,  dim3(NCH),   dim3(128), 0, stream, Wh, zs, idx, oA, oB, VA, VB, SA, PB);
    hipLaunchKernelGGL(k_out,   dim3(GN/4),  dim3(256), 0, stream, s1, zs, VA, VB, SA, PB, out);
}

// Round 2
// 73.152 us; speedup vs baseline: 1.3973x; 1.3973x over previous
//
#include <hip/hip_runtime.h>
#include <math.h>

#define GN 8192
#define GF 64
#define GFIN 256
#define NEG 0.2f
#define NCH 1024
#define CHSZ 8    // GN / NCH

// workspace layout in floats
#define OFF_WH   0
#define OFF_S1   (GN*GF)
#define OFF_S2   (OFF_S1 + GN)
#define OFF_ZS   (OFF_S2 + GN)
#define OFF_IDX  (OFF_ZS + GN)              // int32
#define OFF_VA   (OFF_IDX + GN)
#define OFF_VB   (OFF_VA + (GN+1)*GF)
#define OFF_SA   (OFF_VB + (GN+1)*GF)
#define OFF_PB   (OFF_SA + (GN+1))
#define OFF_CHA  (OFF_PB + (GN+1))          // NCH*GF
#define OFF_CHB  (OFF_CHA + NCH*GF)
#define OFF_SCA  (OFF_CHB + NCH*GF)         // NCH
#define OFF_SCB  (OFF_SCA + NCH)
#define OFF_OA   (OFF_SCB + NCH)            // NCH*GF
#define OFF_OB   (OFF_OA + NCH*GF)
#define OFF_OSA  (OFF_OB + NCH*GF)
#define OFF_OSB  (OFF_OSA + NCH)

// Kernel 1: Wh = h @ W  [N,64], s1 = Wh@a1, s2 = Wh@a2
__global__ __launch_bounds__(512) void k_wh(const float* __restrict__ h,
        const float* __restrict__ W, const float* __restrict__ a,
        float* __restrict__ Wh, float* __restrict__ s1, float* __restrict__ s2) {
    __shared__ float hs[32][GFIN];           // 32 KB
    int t = threadIdx.x;
    int row0 = blockIdx.x * 32;
    const float4* h4 = (const float4*)(h + (size_t)row0 * GFIN);
    float4* hs4 = (float4*)&hs[0][0];
    for (int i = t; i < 32*GFIN/4; i += 512) hs4[i] = h4[i];
    __syncthreads();
    int wave = t >> 6, lane = t & 63;
    float acc[4] = {0.f, 0.f, 0.f, 0.f};
    #pragma unroll 8
    for (int k = 0; k < GFIN; ++k) {
        float wv = W[k*GF + lane];
        #pragma unroll
        for (int q = 0; q < 4; ++q) acc[q] += hs[wave*4+q][k] * wv;
    }
    float a1 = a[lane], a2 = a[GF + lane];
    #pragma unroll
    for (int q = 0; q < 4; ++q) {
        int row = row0 + wave*4 + q;
        Wh[(size_t)row*GF + lane] = acc[q];
        float v1 = acc[q]*a1, v2 = acc[q]*a2;
        #pragma unroll
        for (int o = 32; o > 0; o >>= 1) { v1 += __shfl_xor(v1, o); v2 += __shfl_xor(v2, o); }
        if (lane == 0) { s1[row] = v1; s2[row] = v2; }
    }
}

// Kernel 2: rank-sort s2 (strict total order with index tiebreak -> permutation)
__global__ __launch_bounds__(256) void k_rank(const float* __restrict__ s2v,
        float* __restrict__ zs, int* __restrict__ idx) {
    __shared__ float z[GN];
    int t = threadIdx.x;
    for (int m = t; m < GN; m += 256) z[m] = s2v[m];
    __syncthreads();
    int jl = t >> 3, s = t & 7;              // 32 j's per block, 8 slices each
    int j = blockIdx.x * 32 + jl;
    float zj = z[j];
    int cnt = 0;
    for (int i = 0; i < GN/8; ++i) {
        int m = i*8 + s;
        float zm = z[m];
        cnt += (zm < zj) || (zm == zj && m < j);
    }
    cnt += __shfl_xor(cnt, 1);
    cnt += __shfl_xor(cnt, 2);
    cnt += __shfl_xor(cnt, 4);
    if (s == 0) { zs[cnt] = zj; idx[cnt] = j; }
}

// Kernel 3: per-chunk totals. one wave per chunk; channel = lane; scalar channel
// computed redundantly in all lanes, stored by lane 0.
__global__ __launch_bounds__(256) void k_chunk(const float* __restrict__ Wh,
        const float* __restrict__ zs, const int* __restrict__ idx,
        float* __restrict__ chA, float* __restrict__ chB,
        float* __restrict__ scA, float* __restrict__ scB) {
    int t = threadIdx.x;
    int wave = t >> 6, lane = t & 63;
    int ch = blockIdx.x*4 + wave;
    float Z = zs[GN-1];
    float aAcc = 0.f, bAcc = 0.f, sa = 0.f, sb = 0.f;
    #pragma unroll
    for (int q = 0; q < CHSZ; ++q) {
        int r = ch*CHSZ + q;
        float zr = zs[r];
        int ir = idx[r];
        float tA = expf(zr - Z);
        float tB = expf(NEG * (zr - Z));
        float w = Wh[(size_t)ir*GF + lane];
        aAcc += tA * w; bAcc += tB * w; sa += tA; sb += tB;
    }
    chA[ch*GF + lane] = aAcc;
    chB[ch*GF + lane] = bAcc;
    if (lane == 0) { scA[ch] = sa; scB[ch] = sb; }
}

// Kernel 4: per-channel scans over NCH chunk totals. block c<64: channel c;
// block 64: the two scalar channels. B: exclusive prefix; A: exclusive suffix.
__global__ __launch_bounds__(1024) void k_scan(const float* __restrict__ chA,
        const float* __restrict__ chB, const float* __restrict__ scA,
        const float* __restrict__ scB,
        float* __restrict__ offA, float* __restrict__ offB,
        float* __restrict__ osA, float* __restrict__ osB,
        float* __restrict__ VA, float* __restrict__ VB,
        float* __restrict__ SA, float* __restrict__ PB) {
    __shared__ float buf[NCH];
    int c = blockIdx.x;
    int t = threadIdx.x;
    // ---- B: exclusive prefix over chunk order ----
    float vB = (c < 64) ? chB[t*GF + c] : scB[t];
    buf[t] = vB; __syncthreads();
    for (int o = 1; o < NCH; o <<= 1) {
        float y = (t >= o) ? buf[t-o] : 0.f;
        __syncthreads();
        buf[t] += y;
        __syncthreads();
    }
    float exB = (t > 0) ? buf[t-1] : 0.f;
    float totB = buf[NCH-1];
    if (c < 64) offB[t*GF + c] = exB; else osB[t] = exB;
    if (t == 0) {
        if (c < 64) { VB[(size_t)GN*GF + c] = totB; VA[(size_t)GN*GF + c] = 0.f; }
        else        { PB[GN] = totB; SA[GN] = 0.f; }
    }
    __syncthreads();
    // ---- A: exclusive suffix via reversed prefix ----
    int rt = NCH-1-t;
    float vA = (c < 64) ? chA[rt*GF + c] : scA[rt];
    buf[t] = vA; __syncthreads();
    for (int o = 1; o < NCH; o <<= 1) {
        float y = (t >= o) ? buf[t-o] : 0.f;
        __syncthreads();
        buf[t] += y;
        __syncthreads();
    }
    float exA = (t > 0) ? buf[t-1] : 0.f;
    if (c < 64) offA[rt*GF + c] = exA; else osA[rt] = exA;
}

// Kernel 5: fill full prefix/suffix arrays. one wave per chunk.
// VA[k] = sum_{r>=k} expf(z_r - Z) * w_r   (inclusive suffix)
// VB[k] = sum_{r<k}  expf(0.2(z_r - Z)) * w_r (exclusive prefix)
__global__ __launch_bounds__(256) void k_fill(const float* __restrict__ Wh,
        const float* __restrict__ zs, const int* __restrict__ idx,
        const float* __restrict__ offA, const float* __restrict__ offB,
        const float* __restrict__ osA, const float* __restrict__ osB,
        float* __restrict__ VA, float* __restrict__ VB,
        float* __restrict__ SA, float* __restrict__ PB) {
    int t = threadIdx.x;
    int wave = t >> 6, lane = t & 63;
    int ch = blockIdx.x*4 + wave;
    float Z = zs[GN-1];
    float accA = offA[ch*GF + lane];
    float sAcc = osA[ch];
    #pragma unroll
    for (int q = CHSZ-1; q >= 0; --q) {
        int r = ch*CHSZ + q;
        float zr = zs[r]; int ir = idx[r];
        float w = Wh[(size_t)ir*GF + lane];
        float tA = expf(zr - Z);
        accA += tA * w; sAcc += tA;
        VA[(size_t)r*GF + lane] = accA;
        if (lane == 0) SA[r] = sAcc;
    }
    float accB = offB[ch*GF + lane];
    float sBcc = osB[ch];
    #pragma unroll
    for (int q = 0; q < CHSZ; ++q) {
        int r = ch*CHSZ + q;
        float zr = zs[r]; int ir = idx[r];
        float w = Wh[(size_t)ir*GF + lane];
        VB[(size_t)r*GF + lane] = accB;
        if (lane == 0) PB[r] = sBcc;
        float tB = expf(NEG * (zr - Z));
        accB += tB * w; sBcc += tB;
    }
}

// Kernel 6: per-row output. one wave per row.
__global__ __launch_bounds__(256) void k_out(const float* __restrict__ s1,
        const float* __restrict__ zs,
        const float* __restrict__ VA, const float* __restrict__ VB,
        const float* __restrict__ SA, const float* __restrict__ PB,
        float* __restrict__ out) {
    int t = threadIdx.x;
    int wave = t >> 6, lane = t & 63;
    int i = blockIdx.x*4 + wave;
    float s1i = s1[i];
    float Z = zs[GN-1];
    float g = s1i + Z;
    float m = (g >= 0.f) ? g : NEG*g;        // LeakyReLU(g) = row max of e
    float aA = expf(g - m);                  // <= 1
    float aB = expf(NEG*g - m);              // <= 1
    float tgt = -s1i;
    int lo = 0, hi = GN;                     // lower_bound: first zs[k] >= -s1[i]
    while (lo < hi) { int mid = (lo+hi) >> 1; if (zs[mid] < tgt) lo = mid+1; else hi = mid; }
    int k = lo;
    float va = VA[(size_t)k*GF + lane];
    float vb = VB[(size_t)k*GF + lane];
    float sa = SA[k], pb = PB[k];
    out[(size_t)i*GF + lane] = (aA*va + aB*vb) / (aA*sa + aB*pb);
}

extern "C" void kernel_launch(void* const* d_in, const int* in_sizes, int n_in,
                              void* d_out, int out_size, void* d_ws, size_t ws_size,
                              hipStream_t stream) {
    const float* h = (const float*)d_in[0];
    // d_in[1] = adj (unused by the reference forward)
    const float* W = (const float*)d_in[2];
    const float* a = (const float*)d_in[3];
    float* ws = (float*)d_ws;
    float* Wh  = ws + OFF_WH;
    float* s1  = ws + OFF_S1;
    float* s2  = ws + OFF_S2;
    float* zs  = ws + OFF_ZS;
    int*   idx = (int*)(ws + OFF_IDX);
    float* VA  = ws + OFF_VA;
    float* VB  = ws + OFF_VB;
    float* SA  = ws + OFF_SA;
    float* PB  = ws + OFF_PB;
    float* chA = ws + OFF_CHA;
    float* chB = ws + OFF_CHB;
    float* scA = ws + OFF_SCA;
    float* scB = ws + OFF_SCB;
    float* oA  = ws + OFF_OA;
    float* oB  = ws + OFF_OB;
    float* osA = ws + OFF_OSA;
    float* osB = ws + OFF_OSB;
    float* out = (float*)d_out;

    hipLaunchKernelGGL(k_wh,    dim3(GN/32),  dim3(512),  0, stream, h, W, a, Wh, s1, s2);
    hipLaunchKernelGGL(k_rank,  dim3(GN/32),  dim3(256),  0, stream, s2, zs, idx);
    hipLaunchKernelGGL(k_chunk, dim3(NCH/4),  dim3(256),  0, stream, Wh, zs, idx, chA, chB, scA, scB);
    hipLaunchKernelGGL(k_scan,  dim3(65),     dim3(NCH),  0, stream, chA, chB, scA, scB, oA, oB, osA, osB, VA, VB, SA, PB);
    hipLaunchKernelGGL(k_fill,  dim3(NCH/4),  dim3(256),  0, stream, Wh, zs, idx, oA, oB, osA, osB, VA, VB, SA, PB);
    hipLaunchKernelGGL(k_out,   dim3(GN/4),   dim3(256),  0, stream, s1, zs, VA, VB, SA, PB, out);
}

// Round 3
// 69.811 us; speedup vs baseline: 1.4641x; 1.0479x over previous
//
#include <hip/hip_runtime.h>
#include <math.h>

#define GN 8192
#define GF 64
#define GFIN 256
#define NEG 0.2f
#define NCH 1024
#define CHSZ 8    // GN / NCH

// workspace layout in floats
#define OFF_WH   0
#define OFF_S1   (GN*GF)
#define OFF_S2   (OFF_S1 + GN)
#define OFF_ZS   (OFF_S2 + GN)
#define OFF_IDX  (OFF_ZS + GN)              // int32
#define OFF_CHA  (OFF_IDX + GN)             // NCH*GF
#define OFF_CHB  (OFF_CHA + NCH*GF)
#define OFF_SCA  (OFF_CHB + NCH*GF)         // NCH
#define OFF_SCB  (OFF_SCA + NCH)
#define OFF_OFA  (OFF_SCB + NCH)            // (NCH+1)*GF
#define OFF_OFB  (OFF_OFA + (NCH+1)*GF)
#define OFF_OSA  (OFF_OFB + (NCH+1)*GF)     // NCH+1
#define OFF_OSB  (OFF_OSA + (NCH+1))

// Kernel 1: Wh = h @ W, s1 = Wh@a1, s2 = Wh@a2.
// h read via wave-uniform scalar loads (no LDS pipe); W staged in LDS
// (Wl[k*64+lane]: 2-way bank alias = free per m136).
__global__ __launch_bounds__(256) void k_wh(const float* __restrict__ h,
        const float* __restrict__ W, const float* __restrict__ a,
        float* __restrict__ Wh, float* __restrict__ s1, float* __restrict__ s2) {
    __shared__ float Wl[GFIN*GF];            // 64 KB
    int t = threadIdx.x;
    int lane = t & 63;
    const float4* W4 = (const float4*)W;
    float4* Wl4 = (float4*)Wl;
    #pragma unroll
    for (int m = 0; m < 16; ++m) Wl4[t + m*256] = W4[t + m*256];
    __syncthreads();
    int wid = __builtin_amdgcn_readfirstlane(t >> 6);   // force SGPR wave id
    int row0 = blockIdx.x * 32 + wid * 8;
    const float* hrow = h + (size_t)row0 * GFIN;        // wave-uniform base
    float acc[8] = {0.f,0.f,0.f,0.f,0.f,0.f,0.f,0.f};
    #pragma unroll 8
    for (int k = 0; k < GFIN; ++k) {
        float wv = Wl[k*GF + lane];
        #pragma unroll
        for (int q = 0; q < 8; ++q) acc[q] += hrow[q*GFIN + k] * wv;  // s_load * v
    }
    float a1 = a[lane], a2 = a[GF + lane];
    #pragma unroll
    for (int q = 0; q < 8; ++q) {
        int row = row0 + q;
        Wh[(size_t)row*GF + lane] = acc[q];
        float v1 = acc[q]*a1, v2 = acc[q]*a2;
        #pragma unroll
        for (int o = 32; o > 0; o >>= 1) { v1 += __shfl_xor(v1, o); v2 += __shfl_xor(v2, o); }
        if (lane == 0) { s1[row] = v1; s2[row] = v2; }
    }
}

// Kernel 2: rank-sort s2 via brute-force rank count, float4 LDS reads.
// slice s covers m = i*32 + s*4 + {0..3}: 8 distinct b128 addrs/wave on 8
// distinct bank-quads (conflict-free), 8-lane broadcast groups.
__global__ __launch_bounds__(256) void k_rank(const float* __restrict__ s2v,
        float* __restrict__ zs, int* __restrict__ idx) {
    __shared__ float z[GN];                  // 32 KB
    int t = threadIdx.x;
    const float4* s4 = (const float4*)s2v;
    float4* z4 = (float4*)z;
    for (int m = t; m < GN/4; m += 256) z4[m] = s4[m];
    __syncthreads();
    int jl = t >> 3, s = t & 7;
    int j = blockIdx.x * 32 + jl;
    float zj = z[j];
    int cnt = 0;
    #pragma unroll 4
    for (int i = 0; i < GN/32; ++i) {        // 256 iters
        int m4 = i*8 + s;                    // float4 index = (i*32 + s*4)/4
        float4 v = z4[m4];
        int mb = m4*4;
        cnt += (v.x < zj) || (v.x == zj && mb+0 < j);
        cnt += (v.y < zj) || (v.y == zj && mb+1 < j);
        cnt += (v.z < zj) || (v.z == zj && mb+2 < j);
        cnt += (v.w < zj) || (v.w == zj && mb+3 < j);
    }
    cnt += __shfl_xor(cnt, 1);
    cnt += __shfl_xor(cnt, 2);
    cnt += __shfl_xor(cnt, 4);
    if (s == 0) { zs[cnt] = zj; idx[cnt] = j; }
}

// Kernel 3: per-chunk (8 elems) totals; one wave per chunk, channel = lane,
// scalar channel accumulated redundantly, stored by lane 0.
__global__ __launch_bounds__(256) void k_chunk(const float* __restrict__ Wh,
        const float* __restrict__ zs, const int* __restrict__ idx,
        float* __restrict__ chA, float* __restrict__ chB,
        float* __restrict__ scA, float* __restrict__ scB) {
    int t = threadIdx.x;
    int wid = t >> 6, lane = t & 63;
    int ch = blockIdx.x*4 + wid;
    float Z = zs[GN-1];
    float aAcc = 0.f, bAcc = 0.f, sa = 0.f, sb = 0.f;
    #pragma unroll
    for (int q = 0; q < CHSZ; ++q) {
        int r = ch*CHSZ + q;
        float zr = zs[r];
        int ir = idx[r];
        float d = zr - Z;
        float tA = __expf(d);
        float tB = __expf(NEG * d);
        float w = Wh[(size_t)ir*GF + lane];
        aAcc += tA*w; bAcc += tB*w; sa += tA; sb += tB;
    }
    chA[ch*GF + lane] = aAcc;
    chB[ch*GF + lane] = bAcc;
    if (lane == 0) { scA[ch] = sa; scB[ch] = sb; }
}

// Kernel 4: scans over the NCH chunk totals. 65 blocks x 256 threads.
// blocks 0..63: channel c (B: exclusive prefix, A: exclusive suffix);
// block 64: the scalar channels. reg-serial-4 + wave shuffle scan + LDS combine.
__global__ __launch_bounds__(256) void k_scan(const float* __restrict__ chA,
        const float* __restrict__ chB, const float* __restrict__ scA,
        const float* __restrict__ scB,
        float* __restrict__ offA, float* __restrict__ offB,
        float* __restrict__ osA, float* __restrict__ osB) {
    __shared__ float wsum[4];
    __shared__ float wsum2[4];
    int c = blockIdx.x;
    int t = threadIdx.x;
    int lane = t & 63, wid = t >> 6;
    // ---- B: exclusive prefix over chunks ----
    float v[4];
    #pragma unroll
    for (int q = 0; q < 4; ++q) {
        int ch = t*4 + q;
        v[q] = (c < 64) ? chB[ch*GF + c] : scB[ch];
    }
    float s = v[0]+v[1]+v[2]+v[3];
    float ws = s;
    #pragma unroll
    for (int o = 1; o < 64; o <<= 1) { float y = __shfl_up(ws, o); if (lane >= o) ws += y; }
    if (lane == 63) wsum[wid] = ws;
    __syncthreads();
    float blkoff = 0.f, tot = 0.f;
    #pragma unroll
    for (int w2 = 0; w2 < 4; ++w2) { float x = wsum[w2]; tot += x; if (w2 < wid) blkoff += x; }
    float base = blkoff + ws - s;            // exclusive prefix at chunk 4t
    #pragma unroll
    for (int q = 0; q < 4; ++q) {
        int ch = t*4 + q;
        if (c < 64) offB[ch*GF + c] = base; else osB[ch] = base;
        base += v[q];
    }
    if (t == 0) { if (c < 64) offB[NCH*GF + c] = tot; else osB[NCH] = tot; }
    __syncthreads();
    // ---- A: exclusive suffix (reversed exclusive prefix) ----
    #pragma unroll
    for (int q = 0; q < 4; ++q) {
        int ch = NCH-1 - (t*4 + q);
        v[q] = (c < 64) ? chA[ch*GF + c] : scA[ch];
    }
    s = v[0]+v[1]+v[2]+v[3];
    ws = s;
    #pragma unroll
    for (int o = 1; o < 64; o <<= 1) { float y = __shfl_up(ws, o); if (lane >= o) ws += y; }
    if (lane == 63) wsum2[wid] = ws;
    __syncthreads();
    blkoff = 0.f;
    #pragma unroll
    for (int w2 = 0; w2 < 4; ++w2) { float x = wsum2[w2]; if (w2 < wid) blkoff += x; }
    base = blkoff + ws - s;                  // exclusive suffix at chunk NCH-1-4t
    #pragma unroll
    for (int q = 0; q < 4; ++q) {
        int ch = NCH-1 - (t*4 + q);
        if (c < 64) offA[ch*GF + c] = base; else osA[ch] = base;
        base += v[q];
    }
    if (t == 0) { if (c < 64) offA[NCH*GF + c] = 0.f; else osA[NCH] = 0.f; }
}

// Kernel 5: per-row output. One wave per row: uniform binary search (13 fixed
// steps), chunk-boundary offsets + <=8 exact in-chunk corrections.
__global__ __launch_bounds__(256) void k_out(const float* __restrict__ s1,
        const float* __restrict__ zs, const int* __restrict__ idx,
        const float* __restrict__ Wh,
        const float* __restrict__ offA, const float* __restrict__ offB,
        const float* __restrict__ osA, const float* __restrict__ osB,
        float* __restrict__ out) {
    int t = threadIdx.x;
    int wid = t >> 6, lane = t & 63;
    int i = blockIdx.x*4 + wid;
    float s1i = s1[i];
    float Z = zs[GN-1];
    float g = s1i + Z;
    float m = (g >= 0.f) ? g : NEG*g;        // LeakyReLU(g) = row max of e
    float aA = __expf(g - m);                // <= 1
    float aB = __expf(NEG*g - m);            // <= 1
    float tgt = -s1i;
    int lo = 0, hi = GN;                     // lower_bound: first zs[k] >= tgt
    #pragma unroll
    for (int it = 0; it < 13; ++it) {
        int mid = (lo + hi) >> 1;
        if (zs[mid] < tgt) lo = mid + 1; else hi = mid;
    }
    int k = lo;
    int c0 = k >> 3;                         // CHSZ = 8
    float va, vb, sa, pb;
    if (c0 < NCH) {
        va = offA[c0*GF + lane]; vb = offB[c0*GF + lane];
        sa = osA[c0];            pb = osB[c0];
        #pragma unroll
        for (int q = 0; q < CHSZ; ++q) {
            int r = c0*CHSZ + q;
            float zr = zs[r]; int ir = idx[r];
            float w = Wh[(size_t)ir*GF + lane];
            float d = zr - Z;
            if (r >= k) { float tA = __expf(d);      va += tA*w; sa += tA; }
            else        { float tB = __expf(NEG*d);  vb += tB*w; pb += tB; }
        }
    } else {                                  // k == GN: everything on B side
        va = 0.f; sa = 0.f;
        vb = offB[NCH*GF + lane]; pb = osB[NCH];
    }
    out[(size_t)i*GF + lane] = (aA*va + aB*vb) / (aA*sa + aB*pb);
}

extern "C" void kernel_launch(void* const* d_in, const int* in_sizes, int n_in,
                              void* d_out, int out_size, void* d_ws, size_t ws_size,
                              hipStream_t stream) {
    const float* h = (const float*)d_in[0];
    // d_in[1] = adj (unused by the reference forward)
    const float* W = (const float*)d_in[2];
    const float* a = (const float*)d_in[3];
    float* ws = (float*)d_ws;
    float* Wh  = ws + OFF_WH;
    float* s1  = ws + OFF_S1;
    float* s2  = ws + OFF_S2;
    float* zs  = ws + OFF_ZS;
    int*   idx = (int*)(ws + OFF_IDX);
    float* chA = ws + OFF_CHA;
    float* chB = ws + OFF_CHB;
    float* scA = ws + OFF_SCA;
    float* scB = ws + OFF_SCB;
    float* ofA = ws + OFF_OFA;
    float* ofB = ws + OFF_OFB;
    float* osA = ws + OFF_OSA;
    float* osB = ws + OFF_OSB;
    float* out = (float*)d_out;

    hipLaunchKernelGGL(k_wh,    dim3(GN/32),  dim3(256), 0, stream, h, W, a, Wh, s1, s2);
    hipLaunchKernelGGL(k_rank,  dim3(GN/32),  dim3(256), 0, stream, s2, zs, idx);
    hipLaunchKernelGGL(k_chunk, dim3(NCH/4),  dim3(256), 0, stream, Wh, zs, idx, chA, chB, scA, scB);
    hipLaunchKernelGGL(k_scan,  dim3(65),     dim3(256), 0, stream, chA, chB, scA, scB, ofA, ofB, osA, osB);
    hipLaunchKernelGGL(k_out,   dim3(GN/4),   dim3(256), 0, stream, s1, zs, idx, Wh, ofA, ofB, osA, osB, out);
}